// Round 20
// baseline (318.880 us; speedup 1.0000x reference)
//
#include <hip/hip_runtime.h>
#include <hip/hip_bf16.h>
#include <math.h>

#define B_SZ    2
#define LSEQ    1024
#define D_MODEL 2048
#define D_INNER 4096
#define D_STATE 16
#define DT_RANK 128
#define M_TOK   (B_SZ * LSEQ)      // 2048 token rows
#define SC_NC   32                 // scan chunks per sequence
#define SC_LC   (LSEQ / SC_NC)     // 32 steps per chunk

typedef __attribute__((ext_vector_type(8))) short bf16x8;
typedef __attribute__((ext_vector_type(4))) float f32x4;

__device__ __forceinline__ float softplusf_(float x) {
    return fmaxf(x, 0.f) + log1pf(expf(-fabsf(x)));
}
__device__ __forceinline__ unsigned f2bf(float f) {
    union { float f; unsigned u; } v; v.f = f;
    const unsigned u = v.u;
    return (u + 0x7fffu + ((u >> 16) & 1u)) >> 16;   // RNE, finite inputs
}
__device__ __forceinline__ float bf2f(unsigned u) {
    union { unsigned u; float f; } v; v.u = u << 16; return v.f;
}
__device__ __forceinline__ void gload16(const void* g, void* lds) {
    __builtin_amdgcn_global_load_lds(
        (const __attribute__((address_space(1))) void*)g,
        (__attribute__((address_space(3))) void*)lds, 16, 0, 0);
}

// ===========================================================================
// SINGLE-PHASE 256x256 bf16 MFMA GEMM (r17, proven at MfmaUtil ~42%).
// One vmcnt(0)+barrier per K-tile; depth-1 prefetch suffices (phase >>
// HBM latency). Race ledger: tile t reads buf[db] only (landed per previous
// barrier), stages t+1 into buf[db^1] only (disjoint; its last readers were
// tile t-1, retired before the previous barrier). vmcnt(0)+barrier at phase
// end certifies t+1 landed collectively.
// Swizzle (both sides, verified 0 conflicts): src chunk jj = j^(row&7),
// linear LDS dest; ds_read chunk ch^(row&7).
// epi: 0 = f32 (+ z*zstride, split-K); 5 = dual bf16 (col<4096 -> Cv,
// else Cv2 at col-4096, both ld = ldc).
// ===========================================================================
__global__ __launch_bounds__(512, 2)
void gemm256_1ph(const ushort* __restrict__ A, int lda,
                 const ushort* __restrict__ B, int ldb,
                 void* __restrict__ Cv, int ldc,
                 void* __restrict__ Cv2,
                 int K, int epi, size_t zstride)
{
    __shared__ ushort Lds[2][2][2][128 * 64];   // [dbuf][A/B][half][...]
    const int t    = threadIdx.x;
    const int bm   = blockIdx.y << 8, bn = blockIdx.x << 8;
    const int wave = t >> 6, lane = t & 63;
    const int wm   = wave >> 2;          // 0..1  (64-row slice within half)
    const int wn   = wave & 3;           // 0..3  (32-col slice within half)
    const int lr   = lane & 15, lh = lane >> 4;
    const int kper  = K / gridDim.z;
    const int kbase = blockIdx.z * kper;
    const int nkt   = kper >> 6;

    // staging: issue it in {0,1}: flat = t + it*512; row = flat>>3; j = flat&7
    const ushort* gsA[2]; const ushort* gsB[2];
    int dof[2];
#pragma unroll
    for (int it = 0; it < 2; ++it) {
        const int flat = t + (it << 9);
        const int row  = flat >> 3, j = flat & 7;
        const int jj   = j ^ (row & 7);
        gsA[it] = A + (size_t)(bm + row) * lda + kbase + jj * 8;
        gsB[it] = B + (size_t)(bn + row) * ldb + kbase + jj * 8;
        dof[it] = flat << 3;             // ushort offset (16 B per chunk)
    }

#define STG_A(half, kt, db) do {                                            \
    _Pragma("unroll")                                                       \
    for (int it = 0; it < 2; ++it)                                          \
        gload16(gsA[it] + (size_t)((half) * 128) * lda + (kt) * 64,         \
                &Lds[db][0][half][dof[it]]);                                \
} while (0)
#define STG_B(half, kt, db) do {                                            \
    _Pragma("unroll")                                                       \
    for (int it = 0; it < 2; ++it)                                          \
        gload16(gsB[it] + (size_t)((half) * 128) * ldb + (kt) * 64,         \
                &Lds[db][1][half][dof[it]]);                                \
} while (0)
#define RD_A(db, half) do {                                                 \
    _Pragma("unroll")                                                       \
    for (int mi = 0; mi < 4; ++mi)                                          \
    _Pragma("unroll")                                                       \
    for (int kk = 0; kk < 2; ++kk) {                                        \
        const int row_ = wm * 64 + mi * 16 + lr;                            \
        const int ch_  = ((kk << 2) + lh) ^ (row_ & 7);                     \
        af[mi * 2 + kk] = *(const bf16x8*)((const char*)Lds[db][0][half]    \
                             + row_ * 128 + (ch_ << 4));                    \
    }                                                                       \
} while (0)
#define RD_B(db, half, dst) do {                                            \
    _Pragma("unroll")                                                       \
    for (int nj = 0; nj < 2; ++nj)                                          \
    _Pragma("unroll")                                                       \
    for (int kk = 0; kk < 2; ++kk) {                                        \
        const int row_ = wn * 32 + nj * 16 + lr;                            \
        const int ch_  = ((kk << 2) + lh) ^ (row_ & 7);                     \
        dst[nj * 2 + kk] = *(const bf16x8*)((const char*)Lds[db][1][half]   \
                             + row_ * 128 + (ch_ << 4));                    \
    }                                                                       \
} while (0)
#define MFMA_PAIR(qa, qb, bfa, bfb) do {                                    \
    _Pragma("unroll")                                                       \
    for (int kk = 0; kk < 2; ++kk) {                                        \
        _Pragma("unroll")                                                   \
        for (int mi = 0; mi < 4; ++mi)                                      \
        _Pragma("unroll")                                                   \
        for (int nj = 0; nj < 2; ++nj)                                      \
            acc[qa][mi][nj] = __builtin_amdgcn_mfma_f32_16x16x32_bf16(      \
                af[mi * 2 + kk], bfa[nj * 2 + kk], acc[qa][mi][nj], 0, 0, 0);\
        _Pragma("unroll")                                                   \
        for (int mi = 0; mi < 4; ++mi)                                      \
        _Pragma("unroll")                                                   \
        for (int nj = 0; nj < 2; ++nj)                                      \
            acc[qb][mi][nj] = __builtin_amdgcn_mfma_f32_16x16x32_bf16(      \
                af[mi * 2 + kk], bfb[nj * 2 + kk], acc[qb][mi][nj], 0, 0, 0);\
    }                                                                       \
} while (0)

    f32x4 acc[4][4][2];
#pragma unroll
    for (int q = 0; q < 4; ++q)
#pragma unroll
        for (int i = 0; i < 4; ++i)
#pragma unroll
            for (int j = 0; j < 2; ++j) {
                acc[q][i][j][0] = 0.f; acc[q][i][j][1] = 0.f;
                acc[q][i][j][2] = 0.f; acc[q][i][j][3] = 0.f;
            }

    bf16x8 af[8], bf0[4], bf1[4];

    // prologue: stage tile 0 fully, drain, barrier
    STG_A(0, 0, 0); STG_B(0, 0, 0); STG_B(1, 0, 0); STG_A(1, 0, 0);
    asm volatile("s_waitcnt vmcnt(0)" ::: "memory");
    __builtin_amdgcn_s_barrier();

    for (int kt = 0; kt < nkt; ++kt) {
        const int db = kt & 1;
        RD_A(db, 0); RD_B(db, 0, bf0); RD_B(db, 1, bf1);
        if (kt + 1 < nkt) {
            STG_A(0, kt + 1, db ^ 1); STG_B(0, kt + 1, db ^ 1);
            STG_B(1, kt + 1, db ^ 1); STG_A(1, kt + 1, db ^ 1);
        }
        MFMA_PAIR(0, 1, bf0, bf1);
        RD_A(db, 1);
        MFMA_PAIR(2, 3, bf1, bf0);
        asm volatile("s_waitcnt vmcnt(0)" ::: "memory");
        __builtin_amdgcn_s_barrier();
    }
#undef STG_A
#undef STG_B
#undef RD_A
#undef RD_B
#undef MFMA_PAIR

    float*  C  = (float*)Cv + (size_t)blockIdx.z * zstride;
    ushort* Cb = (ushort*)Cv;
    ushort* C2 = (ushort*)Cv2;
#pragma unroll
    for (int q = 0; q < 4; ++q) {
        const int mh = q >> 1;                        // 0,0,1,1
        const int nh = (q == 1 || q == 2) ? 1 : 0;    // 0,1,1,0
#pragma unroll
        for (int mi = 0; mi < 4; ++mi) {
#pragma unroll
            for (int nj = 0; nj < 2; ++nj) {
                const int col  = bn + nh * 128 + wn * 32 + nj * 16 + lr;
                const int row0 = bm + mh * 128 + wm * 64 + mi * 16 + (lh << 2);
#pragma unroll
                for (int r = 0; r < 4; ++r) {
                    const float v = acc[q][mi][nj][r];
                    if (epi == 0) {
                        C[(size_t)(row0 + r) * ldc + col] = v;
                    } else {  // epi == 5: dual bf16 (fused in_proj)
                        if (col < D_INNER)
                            Cb[(size_t)(row0 + r) * ldc + col] = (ushort)f2bf(v);
                        else
                            C2[(size_t)(row0 + r) * ldc + (col - D_INNER)] = (ushort)f2bf(v);
                    }
                }
            }
        }
    }
}

// ---------------------------------------------------------------------------
// r8 128x128 dbuf GEMM (skinny x_proj / dt_proj shapes). Leading barrier
// KEPT: it pairs with the stage-landing vmcnt (stage-before-read structure).
// epi: 0 = f32 store (split-K via z*zstride); 1 = softplus(v+bias) -> bf16.
// ---------------------------------------------------------------------------
__global__ __launch_bounds__(512, 4)
void gemm_bf16_bt(const ushort* __restrict__ A, int lda,
                  const ushort* __restrict__ B, int ldb,
                  void* __restrict__ Cv, int ldc,
                  const float* __restrict__ bias,
                  int M, int N, int K, int epi, size_t zstride)
{
    __shared__ ushort As[2][128 * 64];
    __shared__ ushort Bs[2][128 * 64];
    const int t    = threadIdx.x;
    const int bm   = blockIdx.y << 7, bn = blockIdx.x << 7;
    const int wave = t >> 6, lane = t & 63;
    const int wr   = (wave >> 2) << 6;
    const int wc   = (wave & 3) << 5;
    const int lr   = lane & 15, lh = lane >> 4;
    const int kper  = K / gridDim.z;
    const int kbase = blockIdx.z * kper;
    const int nkt   = kper >> 6;

    const ushort* ga[2]; const ushort* gb[2];
    int ldof[2];
#pragma unroll
    for (int it = 0; it < 2; ++it) {
        const int seg = wave + (it << 3);
        const int row = (seg << 3) + (lane >> 3);
        const int jj  = (lane & 7) ^ ((lane >> 3) & 7);
        ga[it] = A + (size_t)(bm + row) * lda + kbase + jj * 8;
        int gn = bn + row; gn = gn < N ? gn : N - 1;
        gb[it] = B + (size_t)gn * ldb + kbase + jj * 8;
        ldof[it] = seg << 9;
    }

#define STAGE(bsel) do {                                                \
    _Pragma("unroll")                                                   \
    for (int it = 0; it < 2; ++it) {                                    \
        gload16(ga[it], &As[bsel][ldof[it]]);                           \
        gload16(gb[it], &Bs[bsel][ldof[it]]);                           \
        ga[it] += 64; gb[it] += 64;                                     \
    }                                                                   \
} while (0)

    f32x4 acc[4][2];
#pragma unroll
    for (int i = 0; i < 4; ++i)
#pragma unroll
        for (int j = 0; j < 2; ++j) {
            acc[i][j][0] = 0.f; acc[i][j][1] = 0.f;
            acc[i][j][2] = 0.f; acc[i][j][3] = 0.f;
        }

    STAGE(0);
    for (int kt = 0; kt < nkt; ++kt) {
        const int cur = kt & 1;
        if (kt + 1 < nkt) {
            STAGE(cur ^ 1);
            asm volatile("s_waitcnt vmcnt(4)" ::: "memory");
        } else {
            asm volatile("s_waitcnt vmcnt(0)" ::: "memory");
        }
        __builtin_amdgcn_s_barrier();

        const char* Ab = (const char*)As[cur];
        const char* Bb = (const char*)Bs[cur];
#pragma unroll
        for (int kk = 0; kk < 2; ++kk) {
            bf16x8 af[4], bf[2];
#pragma unroll
            for (int mi = 0; mi < 4; ++mi) {
                const int row = wr + (mi << 4) + lr;
                const int ch  = ((kk << 2) + lh) ^ (row & 7);
                af[mi] = *(const bf16x8*)(Ab + row * 128 + (ch << 4));
            }
#pragma unroll
            for (int nj = 0; nj < 2; ++nj) {
                const int row = wc + (nj << 4) + lr;
                const int ch  = ((kk << 2) + lh) ^ (row & 7);
                bf[nj] = *(const bf16x8*)(Bb + row * 128 + (ch << 4));
            }
#pragma unroll
            for (int mi = 0; mi < 4; ++mi)
#pragma unroll
                for (int nj = 0; nj < 2; ++nj)
                    acc[mi][nj] = __builtin_amdgcn_mfma_f32_16x16x32_bf16(
                        af[mi], bf[nj], acc[mi][nj], 0, 0, 0);
        }
        __builtin_amdgcn_s_barrier();
    }
#undef STAGE

    float*  C  = (float*)Cv + (size_t)blockIdx.z * zstride;
    ushort* Cb = (ushort*)Cv;
#pragma unroll
    for (int mi = 0; mi < 4; ++mi) {
#pragma unroll
        for (int nj = 0; nj < 2; ++nj) {
            const int col  = bn + wc + (nj << 4) + lr;
            const int row0 = bm + wr + (mi << 4) + (lh << 2);
            if (col < N) {
#pragma unroll
                for (int r = 0; r < 4; ++r) {
                    const float v = acc[mi][nj][r];
                    if (epi == 0)
                        C[(size_t)(row0 + r) * ldc + col] = v;
                    else
                        Cb[(size_t)(row0 + r) * ldc + col] =
                            (ushort)f2bf(softplusf_(v + bias[col]));
                }
            }
        }
    }
}

// ---------------------------------------------------------------------------
// Fused 2-segment cvt for step 1 (hs, inw). Targets disjoint from all live
// data.
// ---------------------------------------------------------------------------
#define CVT_N_HS   524288
#define CVT_N_INW  2097152
#define CVT1_E0    (CVT_N_HS)
#define CVT1_E1    (CVT1_E0 + CVT_N_INW)

__global__ __launch_bounds__(256)
void cvt_step1(const float* __restrict__ hs,  ushort* __restrict__ hsb,
               const float* __restrict__ inw, ushort* __restrict__ inwb)
{
    for (int i = blockIdx.x * 256 + threadIdx.x; i < CVT1_E1; i += gridDim.x * 256) {
        const float* in; ushort* out; int j;
        if (i < CVT1_E0) { in = hs;  out = hsb;  j = i; }
        else             { in = inw; out = inwb; j = i - CVT1_E0; }
        const float4 v0 = ((const float4*)in)[j * 2];
        const float4 v1 = ((const float4*)in)[j * 2 + 1];
        int4 p;
        p.x = (int)(f2bf(v0.x) | (f2bf(v0.y) << 16));
        p.y = (int)(f2bf(v0.z) | (f2bf(v0.w) << 16));
        p.z = (int)(f2bf(v1.x) | (f2bf(v1.y) << 16));
        p.w = (int)(f2bf(v1.z) | (f2bf(v1.w) << 16));
        ((int4*)out)[j] = p;
    }
}

// ---------------------------------------------------------------------------
// Fused 3-segment cvt for step 4 (ow, xw, dtw). Targets first written here:
// owb over dead xraw, xwb/dtwb over dead inwb. Read at steps 5/6/8.
// ---------------------------------------------------------------------------
#define CVT_N_OW   1048576
#define CVT_N_XW   81920
#define CVT_N_DTW  65536
#define CVT4_E0    (CVT_N_OW)
#define CVT4_E1    (CVT4_E0 + CVT_N_XW)
#define CVT4_E2    (CVT4_E1 + CVT_N_DTW)

__global__ __launch_bounds__(256)
void cvt_step4(const float* __restrict__ ow,  ushort* __restrict__ owb,
               const float* __restrict__ xw,  ushort* __restrict__ xwb,
               const float* __restrict__ dtw, ushort* __restrict__ dtwb)
{
    for (int i = blockIdx.x * 256 + threadIdx.x; i < CVT4_E2; i += gridDim.x * 256) {
        const float* in; ushort* out; int j;
        if (i < CVT4_E0)      { in = ow;  out = owb;  j = i; }
        else if (i < CVT4_E1) { in = xw;  out = xwb;  j = i - CVT4_E0; }
        else                  { in = dtw; out = dtwb; j = i - CVT4_E1; }
        const float4 v0 = ((const float4*)in)[j * 2];
        const float4 v1 = ((const float4*)in)[j * 2 + 1];
        int4 p;
        p.x = (int)(f2bf(v0.x) | (f2bf(v0.y) << 16));
        p.y = (int)(f2bf(v0.z) | (f2bf(v0.w) << 16));
        p.z = (int)(f2bf(v1.x) | (f2bf(v1.y) << 16));
        p.w = (int)(f2bf(v1.z) | (f2bf(v1.w) << 16));
        ((int4*)out)[j] = p;
    }
}

// ---------------------------------------------------------------------------
__global__ __launch_bounds__(256)
void reduce_out4(const float* __restrict__ part, float* __restrict__ out, int n4)
{
    const int stride = M_TOK * D_MODEL / 4;   // float4 units per slice
    for (int i = blockIdx.x * 256 + threadIdx.x; i < n4; i += gridDim.x * 256) {
        const float4 a = ((const float4*)part)[i];
        const float4 b = ((const float4*)part)[i + stride];
        const float4 c = ((const float4*)part)[i + 2 * stride];
        const float4 d = ((const float4*)part)[i + 3 * stride];
        ((float4*)out)[i] = make_float4(a.x + b.x + c.x + d.x,
                                        a.y + b.y + c.y + d.y,
                                        a.z + b.z + c.z + d.z,
                                        a.w + b.w + c.w + d.w);
    }
}

// ---------------------------------------------------------------------------
// Depthwise causal conv (K=4) + bias + SiLU, m-chunked register window.
// ---------------------------------------------------------------------------
__global__ __launch_bounds__(256)
void conv_silu_k(const ushort* __restrict__ xraw,
                 const float* __restrict__ cw,
                 const float* __restrict__ cb,
                 ushort* __restrict__ xb)
{
    const int d  = (blockIdx.x << 8) + threadIdx.x;
    const int m0 = blockIdx.y << 6;
    const int l0 = m0 & (LSEQ - 1);
    const float4 w = *(const float4*)&cw[d << 2];
    const float bias = cb[d];
    float x3 = 0.f, x2 = 0.f, x1 = 0.f;
    if (l0 > 0) {
        x3 = bf2f(xraw[(size_t)(m0 - 3) * D_INNER + d]);
        x2 = bf2f(xraw[(size_t)(m0 - 2) * D_INNER + d]);
        x1 = bf2f(xraw[(size_t)(m0 - 1) * D_INNER + d]);
    }
#pragma unroll 4
    for (int i = 0; i < 64; ++i) {
        const size_t m = (size_t)m0 + i;
        const float x0 = bf2f(xraw[m * D_INNER + d]);
        float acc = bias;
        acc = fmaf(w.x, x3, acc);
        acc = fmaf(w.y, x2, acc);
        acc = fmaf(w.z, x1, acc);
        acc = fmaf(w.w, x0, acc);
        const float sg = 1.f / (1.f + expf(-acc));
        xb[m * D_INNER + d] = (ushort)f2bf(acc * sg);
        x3 = x2; x2 = x1; x1 = x0;
    }
}

// ---------------------------------------------------------------------------
__global__ __launch_bounds__(256)
void reduce_ssm(const float* __restrict__ part,
                float* __restrict__ ssmf, ushort* __restrict__ ssmb)
{
    const int i = blockIdx.x * 256 + threadIdx.x;
    float v = 0.f;
#pragma unroll
    for (int z = 0; z < 8; ++z) v += part[(size_t)z * (M_TOK * 160) + i];
    ssmf[i] = v;
    ssmb[i] = (ushort)f2bf(v);
}

// ===========================================================================
// FUSED chunked selective scan (r20: 1024-thread blocks for occupancy).
// r19 diagnosis: scan is VALU/latency-bound (VALUBusy 60%, occ 19.7% = one
// 512-thr block/CU; FETCH and conflicts fixed but time unchanged). r20:
// block = 32 d x 32 chunks = 1024 thr, grid (128,2) = 256 = 1/CU but now
// 16 waves/CU (4/SIMD) -> VALUBusy toward ceiling. SC_NC=32, SC_LC=32.
// LDS [32c][32d][17] f32 x2 = 139 KB <= 160 (large static LDS proven by the
// GEMM's 128 KB). Bank: slot=(c*32+dl)*17+s scalar -> bank=(dl*17+s)%32,
// 17 odd => permutation over dl => <=2-way (free). Pass2: 512 (dl,s) pairs,
// serial 32-chunk prefix, same op order as 3-pass. Chunk regrouping 16->32
// changes FP association at chunk boundaries only (same algebra).
// ===========================================================================
__global__ __launch_bounds__(1024)
void scan_fused(const ushort* __restrict__ dtp,   // dt bf16 [M][4096]
                ushort* __restrict__ xb,          // x bf16 in / y bf16 out
                const ushort* __restrict__ gb,    // gate bf16
                const float* __restrict__ ssm,    // [M][160], B@128+s, C@144+s
                const float* __restrict__ Ap,     // [4096][16]
                const float* __restrict__ Dp)     // [4096]
{
    __shared__ float Pl[SC_NC * 32 * 17];
    __shared__ float Ql[SC_NC * 32 * 17];
    const int t  = threadIdx.x;
    const int dl = t & 31, c = t >> 5;            // c = 0..31
    const int d  = (blockIdx.x << 5) + dl;
    const int b  = blockIdx.y;
    const int base = (c * 32 + dl) * 17;

    float a[16];
    *(float4*)&a[0]  = *(const float4*)&Ap[d * 16];
    *(float4*)&a[4]  = *(const float4*)&Ap[d * 16 + 4];
    *(float4*)&a[8]  = *(const float4*)&Ap[d * 16 + 8];
    *(float4*)&a[12] = *(const float4*)&Ap[d * 16 + 12];
    const size_t m0 = (size_t)b * LSEQ + (size_t)c * SC_LC;

    // ---- pass 1: per-chunk (P, q) ----
    float q[16];
#pragma unroll
    for (int s = 0; s < 16; ++s) q[s] = 0.f;
    float dtsum = 0.f;
#pragma unroll 2
    for (int l = 0; l < SC_LC; ++l) {
        const size_t m = m0 + l;
        const float dt = bf2f(dtp[m * D_INNER + d]);
        const float xv = bf2f(xb[m * D_INNER + d]);
        const float4 B0 = *(const float4*)&ssm[m * 160 + 128];
        const float4 B1 = *(const float4*)&ssm[m * 160 + 132];
        const float4 B2 = *(const float4*)&ssm[m * 160 + 136];
        const float4 B3 = *(const float4*)&ssm[m * 160 + 140];
        const float Bv[16] = {B0.x,B0.y,B0.z,B0.w, B1.x,B1.y,B1.z,B1.w,
                              B2.x,B2.y,B2.z,B2.w, B3.x,B3.y,B3.z,B3.w};
        const float t1 = dt * xv;
#pragma unroll
        for (int s = 0; s < 16; ++s) {
            const float dA = __expf(dt * a[s]);
            q[s] = fmaf(q[s], dA, t1 * Bv[s]);
        }
        dtsum += dt;
    }
#pragma unroll
    for (int s = 0; s < 16; ++s) {
        Pl[base + s] = __expf(a[s] * dtsum);
        Ql[base + s] = q[s];
    }
    __syncthreads();

    // ---- pass 2: cross-chunk prefix; 512 (dl2, s2) pairs ----
    if (t < 512) {
        const int dl2 = t >> 4, s2 = t & 15;
        float st2 = 0.f;
#pragma unroll
        for (int c2 = 0; c2 < SC_NC; ++c2) {
            const int idx = (c2 * 32 + dl2) * 17 + s2;
            const float Pv = Pl[idx];
            const float qv = Ql[idx];
            Ql[idx] = st2;                 // state entering chunk c2
            st2 = fmaf(st2, Pv, qv);
        }
    }
    __syncthreads();

    // ---- pass 3: rescan with correct initial state; writes y over xb ----
    float st[16];
#pragma unroll
    for (int s = 0; s < 16; ++s) st[s] = Ql[base + s];
    const float Dd = Dp[d];
#pragma unroll 2
    for (int l = 0; l < SC_LC; ++l) {
        const size_t m = m0 + l;
        const float dt = bf2f(dtp[m * D_INNER + d]);
        const float xv = bf2f(xb[m * D_INNER + d]);
        const float gv = bf2f(gb[m * D_INNER + d]);
        const float4 B0 = *(const float4*)&ssm[m * 160 + 128];
        const float4 B1 = *(const float4*)&ssm[m * 160 + 132];
        const float4 B2 = *(const float4*)&ssm[m * 160 + 136];
        const float4 B3 = *(const float4*)&ssm[m * 160 + 140];
        const float4 C0 = *(const float4*)&ssm[m * 160 + 144];
        const float4 C1 = *(const float4*)&ssm[m * 160 + 148];
        const float4 C2 = *(const float4*)&ssm[m * 160 + 152];
        const float4 C3 = *(const float4*)&ssm[m * 160 + 156];
        const float Bv[16] = {B0.x,B0.y,B0.z,B0.w, B1.x,B1.y,B1.z,B1.w,
                              B2.x,B2.y,B2.z,B2.w, B3.x,B3.y,B3.z,B3.w};
        const float Cv[16] = {C0.x,C0.y,C0.z,C0.w, C1.x,C1.y,C1.z,C1.w,
                              C2.x,C2.y,C2.z,C2.w, C3.x,C3.y,C3.z,C3.w};
        const float t1 = dt * xv;
        float y = 0.f;
#pragma unroll
        for (int s = 0; s < 16; ++s) {
            const float dA = __expf(dt * a[s]);
            st[s] = fmaf(st[s], dA, t1 * Bv[s]);
            y = fmaf(st[s], Cv[s], y);
        }
        const float yg  = fmaf(Dd, xv, y);
        const float sig = 1.f / (1.f + expf(-gv));
        xb[m * D_INNER + d] = (ushort)f2bf(yg * (gv * sig));
    }
}

// ---------------------------------------------------------------------------
extern "C" void kernel_launch(void* const* d_in, const int* in_sizes, int n_in,
                              void* d_out, int out_size, void* d_ws, size_t ws_size,
                              hipStream_t stream)
{
    (void)in_sizes; (void)n_in; (void)out_size; (void)ws_size;
    const float* hs  = (const float*)d_in[0];  // [2048,2048]
    const float* inw = (const float*)d_in[1];  // [8192,2048]
    const float* cw  = (const float*)d_in[2];  // [4096,4]
    const float* cb  = (const float*)d_in[3];  // [4096]
    const float* xw  = (const float*)d_in[4];  // [160,4096]
    const float* dtw = (const float*)d_in[5];  // [4096,128]
    const float* dtb = (const float*)d_in[6];  // [4096]
    const float* Ap  = (const float*)d_in[7];  // [4096,16]
    const float* Dp  = (const float*)d_in[8];  // [4096]
    const float* ow  = (const float*)d_in[9];  // [2048,4096]
    float* out = (float*)d_out;                // [2048,2048]

    // ------------------------------------------------------------------
    // Workspace plan: IDENTICAL to the proven round-10..19 layout
    // (100.7 MB, bf16 sizes f32-EQUIV = ushort_count/2, timeline audited).
    // xwb/dtwb live INSIDE inwb's span — written only at step 4 (after
    // in_proj consumed inwb); cvt_step1 touches only hsb+inwb.
    // ------------------------------------------------------------------
    float*  ws    = (float*)d_ws;
    float*  P     = ws;                          // [0, 16777216)        step 8
    ushort* hsb   = (ushort*)(ws + 0);           // [0, 2097152)         steps 1-2
    ushort* inwb  = (ushort*)(ws + 2097152);     // [2097152, 10485760)  steps 1-2
    ushort* dtb16 = (ushort*)(ws + 0);           // [0, 4194304)         steps 6-7
    ushort* xwb   = (ushort*)(ws + 4194304);     // [4194304, 4521984)   steps 4-5
    ushort* dtwb  = (ushort*)(ws + 4521984);     // [4521984, 4784128)   steps 4-6
    float*  ssmf  = ws + 4784128;                // [4784128, 5111808)   steps 5-7
    ushort* ssmb  = (ushort*)(ws + 5111808);     // [5111808, 5275648)   steps 5-6
    float*  part  = ws + 5275648;                // [5275648, 7897088)   step 5
    ushort* pg    = (ushort*)(ws + 10485760);    // [10485760, 14680064) steps 2-7
    ushort* xtb   = (ushort*)(ws + 16777216);    // [16777216, 20971520) steps 3-8
    ushort* xraw  = (ushort*)(ws + 20971520);    // [20971520, 25165824) steps 2-3
    ushort* owb   = (ushort*)(ws + 20971520);    // same region,         steps 4-8

    const dim3 blk(256);
    const dim3 blk512(512);
    const dim3 blk1024(1024);

    // 1) fused cvt of in_proj inputs only (hs, inw)
    cvt_step1<<<dim3(2048), blk, 0, stream>>>(hs, hsb, inw, inwb);

    // 2) in_proj (fused x+gate): [2048 x 8192], single-phase 256^2 engine
    gemm256_1ph<<<dim3(32, 8, 1), blk512, 0, stream>>>(
        hsb, D_MODEL, inwb, D_MODEL, xraw, D_INNER, pg, D_MODEL, 5, 0);

    // 3) conv + SiLU: xraw -> xtb
    conv_silu_k<<<dim3(16, 32), blk, 0, stream>>>(xraw, cw, cb, xtb);

    // 4) fused cvt of remaining weights (ow, xw, dtw) — targets all dead now
    cvt_step4<<<dim3(2048), blk, 0, stream>>>(ow, owb, xw, xwb, dtw, dtwb);

    // 5) x_proj split-K x8 -> part; reduce -> ssmf/ssmb
    gemm_bf16_bt<<<dim3(2, 16, 8), blk512, 0, stream>>>(
        xtb, D_INNER, xwb, D_INNER, part, 160, nullptr,
        M_TOK, 160, D_INNER, 0, (size_t)M_TOK * 160);
    reduce_ssm<<<dim3(1280), blk, 0, stream>>>(part, ssmf, ssmb);

    // 6) dt_proj + softplus(+bias) -> dtb16
    gemm_bf16_bt<<<dim3(32, 16, 1), blk512, 0, stream>>>(
        ssmb, 160, dtwb, DT_RANK, dtb16, D_INNER, dtb,
        M_TOK, D_INNER, DT_RANK, 1, 0);

    // 7) FUSED chunked selective scan (+ D-skip + gate), y bf16 over xtb
    scan_fused<<<dim3(D_INNER / 32, B_SZ), blk1024, 0, stream>>>(
        dtb16, xtb, pg, ssmf, Ap, Dp);

    // 8) out_proj: single-phase 256^2, split-K x4 -> P; reduce4 -> out
    gemm256_1ph<<<dim3(8, 8, 4), blk512, 0, stream>>>(
        xtb, D_INNER, owb, D_INNER, P, D_MODEL, nullptr,
        D_INNER, 0, (size_t)M_TOK * D_MODEL);
    reduce_out4<<<dim3(1024), blk, 0, stream>>>(P, out, (M_TOK * D_MODEL) / 4);
}

// Round 21
// 288.416 us; speedup vs baseline: 1.1056x; 1.1056x over previous
//
#include <hip/hip_runtime.h>
#include <hip/hip_bf16.h>
#include <math.h>

#define B_SZ    2
#define LSEQ    1024
#define D_MODEL 2048
#define D_INNER 4096
#define D_STATE 16
#define DT_RANK 128
#define M_TOK   (B_SZ * LSEQ)      // 2048 token rows
#define NCHUNK  16
#define LCHUNK  (LSEQ / NCHUNK)    // 64
#define LOG2E   1.4426950408889634f

typedef __attribute__((ext_vector_type(8))) short bf16x8;
typedef __attribute__((ext_vector_type(4))) float f32x4;

__device__ __forceinline__ float softplusf_(float x) {
    return fmaxf(x, 0.f) + log1pf(expf(-fabsf(x)));
}
__device__ __forceinline__ unsigned f2bf(float f) {
    union { float f; unsigned u; } v; v.f = f;
    const unsigned u = v.u;
    return (u + 0x7fffu + ((u >> 16) & 1u)) >> 16;   // RNE, finite inputs
}
__device__ __forceinline__ float bf2f(unsigned u) {
    union { unsigned u; float f; } v; v.u = u << 16; return v.f;
}
__device__ __forceinline__ void gload16(const void* g, void* lds) {
    __builtin_amdgcn_global_load_lds(
        (const __attribute__((address_space(1))) void*)g,
        (__attribute__((address_space(3))) void*)lds, 16, 0, 0);
}
__device__ __forceinline__ float exp2fast(float x) {
    return __builtin_amdgcn_exp2f(x);    // v_exp_f32: 2^x
}

// ===========================================================================
// SINGLE-PHASE 256x256 bf16 MFMA GEMM (r17, proven at MfmaUtil ~42%).
// One vmcnt(0)+barrier per K-tile; depth-1 prefetch suffices (phase >>
// HBM latency). Race ledger: tile t reads buf[db] only (landed per previous
// barrier), stages t+1 into buf[db^1] only (disjoint; its last readers were
// tile t-1, retired before the previous barrier). vmcnt(0)+barrier at phase
// end certifies t+1 landed collectively.
// Swizzle (both sides, verified 0 conflicts): src chunk jj = j^(row&7),
// linear LDS dest; ds_read chunk ch^(row&7).
// epi: 0 = f32 (+ z*zstride, split-K); 5 = dual bf16 (col<4096 -> Cv,
// else Cv2 at col-4096, both ld = ldc).
// ===========================================================================
__global__ __launch_bounds__(512, 2)
void gemm256_1ph(const ushort* __restrict__ A, int lda,
                 const ushort* __restrict__ B, int ldb,
                 void* __restrict__ Cv, int ldc,
                 void* __restrict__ Cv2,
                 int K, int epi, size_t zstride)
{
    __shared__ ushort Lds[2][2][2][128 * 64];   // [dbuf][A/B][half][...]
    const int t    = threadIdx.x;
    const int bm   = blockIdx.y << 8, bn = blockIdx.x << 8;
    const int wave = t >> 6, lane = t & 63;
    const int wm   = wave >> 2;          // 0..1  (64-row slice within half)
    const int wn   = wave & 3;           // 0..3  (32-col slice within half)
    const int lr   = lane & 15, lh = lane >> 4;
    const int kper  = K / gridDim.z;
    const int kbase = blockIdx.z * kper;
    const int nkt   = kper >> 6;

    // staging: issue it in {0,1}: flat = t + it*512; row = flat>>3; j = flat&7
    const ushort* gsA[2]; const ushort* gsB[2];
    int dof[2];
#pragma unroll
    for (int it = 0; it < 2; ++it) {
        const int flat = t + (it << 9);
        const int row  = flat >> 3, j = flat & 7;
        const int jj   = j ^ (row & 7);
        gsA[it] = A + (size_t)(bm + row) * lda + kbase + jj * 8;
        gsB[it] = B + (size_t)(bn + row) * ldb + kbase + jj * 8;
        dof[it] = flat << 3;             // ushort offset (16 B per chunk)
    }

#define STG_A(half, kt, db) do {                                            \
    _Pragma("unroll")                                                       \
    for (int it = 0; it < 2; ++it)                                          \
        gload16(gsA[it] + (size_t)((half) * 128) * lda + (kt) * 64,         \
                &Lds[db][0][half][dof[it]]);                                \
} while (0)
#define STG_B(half, kt, db) do {                                            \
    _Pragma("unroll")                                                       \
    for (int it = 0; it < 2; ++it)                                          \
        gload16(gsB[it] + (size_t)((half) * 128) * ldb + (kt) * 64,         \
                &Lds[db][1][half][dof[it]]);                                \
} while (0)
#define RD_A(db, half) do {                                                 \
    _Pragma("unroll")                                                       \
    for (int mi = 0; mi < 4; ++mi)                                          \
    _Pragma("unroll")                                                       \
    for (int kk = 0; kk < 2; ++kk) {                                        \
        const int row_ = wm * 64 + mi * 16 + lr;                            \
        const int ch_  = ((kk << 2) + lh) ^ (row_ & 7);                     \
        af[mi * 2 + kk] = *(const bf16x8*)((const char*)Lds[db][0][half]    \
                             + row_ * 128 + (ch_ << 4));                    \
    }                                                                       \
} while (0)
#define RD_B(db, half, dst) do {                                            \
    _Pragma("unroll")                                                       \
    for (int nj = 0; nj < 2; ++nj)                                          \
    _Pragma("unroll")                                                       \
    for (int kk = 0; kk < 2; ++kk) {                                        \
        const int row_ = wn * 32 + nj * 16 + lr;                            \
        const int ch_  = ((kk << 2) + lh) ^ (row_ & 7);                     \
        dst[nj * 2 + kk] = *(const bf16x8*)((const char*)Lds[db][1][half]   \
                             + row_ * 128 + (ch_ << 4));                    \
    }                                                                       \
} while (0)
#define MFMA_PAIR(qa, qb, bfa, bfb) do {                                    \
    _Pragma("unroll")                                                       \
    for (int kk = 0; kk < 2; ++kk) {                                        \
        _Pragma("unroll")                                                   \
        for (int mi = 0; mi < 4; ++mi)                                      \
        _Pragma("unroll")                                                   \
        for (int nj = 0; nj < 2; ++nj)                                      \
            acc[qa][mi][nj] = __builtin_amdgcn_mfma_f32_16x16x32_bf16(      \
                af[mi * 2 + kk], bfa[nj * 2 + kk], acc[qa][mi][nj], 0, 0, 0);\
        _Pragma("unroll")                                                   \
        for (int mi = 0; mi < 4; ++mi)                                      \
        _Pragma("unroll")                                                   \
        for (int nj = 0; nj < 2; ++nj)                                      \
            acc[qb][mi][nj] = __builtin_amdgcn_mfma_f32_16x16x32_bf16(      \
                af[mi * 2 + kk], bfb[nj * 2 + kk], acc[qb][mi][nj], 0, 0, 0);\
    }                                                                       \
} while (0)

    f32x4 acc[4][4][2];
#pragma unroll
    for (int q = 0; q < 4; ++q)
#pragma unroll
        for (int i = 0; i < 4; ++i)
#pragma unroll
            for (int j = 0; j < 2; ++j) {
                acc[q][i][j][0] = 0.f; acc[q][i][j][1] = 0.f;
                acc[q][i][j][2] = 0.f; acc[q][i][j][3] = 0.f;
            }

    bf16x8 af[8], bf0[4], bf1[4];

    // prologue: stage tile 0 fully, drain, barrier
    STG_A(0, 0, 0); STG_B(0, 0, 0); STG_B(1, 0, 0); STG_A(1, 0, 0);
    asm volatile("s_waitcnt vmcnt(0)" ::: "memory");
    __builtin_amdgcn_s_barrier();

    for (int kt = 0; kt < nkt; ++kt) {
        const int db = kt & 1;
        RD_A(db, 0); RD_B(db, 0, bf0); RD_B(db, 1, bf1);
        if (kt + 1 < nkt) {
            STG_A(0, kt + 1, db ^ 1); STG_B(0, kt + 1, db ^ 1);
            STG_B(1, kt + 1, db ^ 1); STG_A(1, kt + 1, db ^ 1);
        }
        MFMA_PAIR(0, 1, bf0, bf1);
        RD_A(db, 1);
        MFMA_PAIR(2, 3, bf1, bf0);
        asm volatile("s_waitcnt vmcnt(0)" ::: "memory");
        __builtin_amdgcn_s_barrier();
    }
#undef STG_A
#undef STG_B
#undef RD_A
#undef RD_B
#undef MFMA_PAIR

    float*  C  = (float*)Cv + (size_t)blockIdx.z * zstride;
    ushort* Cb = (ushort*)Cv;
    ushort* C2 = (ushort*)Cv2;
#pragma unroll
    for (int q = 0; q < 4; ++q) {
        const int mh = q >> 1;                        // 0,0,1,1
        const int nh = (q == 1 || q == 2) ? 1 : 0;    // 0,1,1,0
#pragma unroll
        for (int mi = 0; mi < 4; ++mi) {
#pragma unroll
            for (int nj = 0; nj < 2; ++nj) {
                const int col  = bn + nh * 128 + wn * 32 + nj * 16 + lr;
                const int row0 = bm + mh * 128 + wm * 64 + mi * 16 + (lh << 2);
#pragma unroll
                for (int r = 0; r < 4; ++r) {
                    const float v = acc[q][mi][nj][r];
                    if (epi == 0) {
                        C[(size_t)(row0 + r) * ldc + col] = v;
                    } else {  // epi == 5: dual bf16 (fused in_proj)
                        if (col < D_INNER)
                            Cb[(size_t)(row0 + r) * ldc + col] = (ushort)f2bf(v);
                        else
                            C2[(size_t)(row0 + r) * ldc + (col - D_INNER)] = (ushort)f2bf(v);
                    }
                }
            }
        }
    }
}

// ---------------------------------------------------------------------------
// r8 128x128 dbuf GEMM (skinny x_proj / dt_proj shapes). Leading barrier
// KEPT: it pairs with the stage-landing vmcnt (stage-before-read structure).
// epi: 0 = f32 store (split-K via z*zstride); 1 = softplus(v+bias) -> bf16.
// ---------------------------------------------------------------------------
__global__ __launch_bounds__(512, 4)
void gemm_bf16_bt(const ushort* __restrict__ A, int lda,
                  const ushort* __restrict__ B, int ldb,
                  void* __restrict__ Cv, int ldc,
                  const float* __restrict__ bias,
                  int M, int N, int K, int epi, size_t zstride)
{
    __shared__ ushort As[2][128 * 64];
    __shared__ ushort Bs[2][128 * 64];
    const int t    = threadIdx.x;
    const int bm   = blockIdx.y << 7, bn = blockIdx.x << 7;
    const int wave = t >> 6, lane = t & 63;
    const int wr   = (wave >> 2) << 6;
    const int wc   = (wave & 3) << 5;
    const int lr   = lane & 15, lh = lane >> 4;
    const int kper  = K / gridDim.z;
    const int kbase = blockIdx.z * kper;
    const int nkt   = kper >> 6;

    const ushort* ga[2]; const ushort* gb[2];
    int ldof[2];
#pragma unroll
    for (int it = 0; it < 2; ++it) {
        const int seg = wave + (it << 3);
        const int row = (seg << 3) + (lane >> 3);
        const int jj  = (lane & 7) ^ ((lane >> 3) & 7);
        ga[it] = A + (size_t)(bm + row) * lda + kbase + jj * 8;
        int gn = bn + row; gn = gn < N ? gn : N - 1;
        gb[it] = B + (size_t)gn * ldb + kbase + jj * 8;
        ldof[it] = seg << 9;
    }

#define STAGE(bsel) do {                                                \
    _Pragma("unroll")                                                   \
    for (int it = 0; it < 2; ++it) {                                    \
        gload16(ga[it], &As[bsel][ldof[it]]);                           \
        gload16(gb[it], &Bs[bsel][ldof[it]]);                           \
        ga[it] += 64; gb[it] += 64;                                     \
    }                                                                   \
} while (0)

    f32x4 acc[4][2];
#pragma unroll
    for (int i = 0; i < 4; ++i)
#pragma unroll
        for (int j = 0; j < 2; ++j) {
            acc[i][j][0] = 0.f; acc[i][j][1] = 0.f;
            acc[i][j][2] = 0.f; acc[i][j][3] = 0.f;
        }

    STAGE(0);
    for (int kt = 0; kt < nkt; ++kt) {
        const int cur = kt & 1;
        if (kt + 1 < nkt) {
            STAGE(cur ^ 1);
            asm volatile("s_waitcnt vmcnt(4)" ::: "memory");
        } else {
            asm volatile("s_waitcnt vmcnt(0)" ::: "memory");
        }
        __builtin_amdgcn_s_barrier();

        const char* Ab = (const char*)As[cur];
        const char* Bb = (const char*)Bs[cur];
#pragma unroll
        for (int kk = 0; kk < 2; ++kk) {
            bf16x8 af[4], bf[2];
#pragma unroll
            for (int mi = 0; mi < 4; ++mi) {
                const int row = wr + (mi << 4) + lr;
                const int ch  = ((kk << 2) + lh) ^ (row & 7);
                af[mi] = *(const bf16x8*)(Ab + row * 128 + (ch << 4));
            }
#pragma unroll
            for (int nj = 0; nj < 2; ++nj) {
                const int row = wc + (nj << 4) + lr;
                const int ch  = ((kk << 2) + lh) ^ (row & 7);
                bf[nj] = *(const bf16x8*)(Bb + row * 128 + (ch << 4));
            }
#pragma unroll
            for (int mi = 0; mi < 4; ++mi)
#pragma unroll
                for (int nj = 0; nj < 2; ++nj)
                    acc[mi][nj] = __builtin_amdgcn_mfma_f32_16x16x32_bf16(
                        af[mi], bf[nj], acc[mi][nj], 0, 0, 0);
        }
        __builtin_amdgcn_s_barrier();
    }
#undef STAGE

    float*  C  = (float*)Cv + (size_t)blockIdx.z * zstride;
    ushort* Cb = (ushort*)Cv;
#pragma unroll
    for (int mi = 0; mi < 4; ++mi) {
#pragma unroll
        for (int nj = 0; nj < 2; ++nj) {
            const int col  = bn + wc + (nj << 4) + lr;
            const int row0 = bm + wr + (mi << 4) + (lh << 2);
            if (col < N) {
#pragma unroll
                for (int r = 0; r < 4; ++r) {
                    const float v = acc[mi][nj][r];
                    if (epi == 0)
                        C[(size_t)(row0 + r) * ldc + col] = v;
                    else
                        Cb[(size_t)(row0 + r) * ldc + col] =
                            (ushort)f2bf(softplusf_(v + bias[col]));
                }
            }
        }
    }
}

// ---------------------------------------------------------------------------
// Fused 2-segment cvt for step 1 (hs, inw). Targets disjoint from all live
// data.
// ---------------------------------------------------------------------------
#define CVT_N_HS   524288
#define CVT_N_INW  2097152
#define CVT1_E0    (CVT_N_HS)
#define CVT1_E1    (CVT1_E0 + CVT_N_INW)

__global__ __launch_bounds__(256)
void cvt_step1(const float* __restrict__ hs,  ushort* __restrict__ hsb,
               const float* __restrict__ inw, ushort* __restrict__ inwb)
{
    for (int i = blockIdx.x * 256 + threadIdx.x; i < CVT1_E1; i += gridDim.x * 256) {
        const float* in; ushort* out; int j;
        if (i < CVT1_E0) { in = hs;  out = hsb;  j = i; }
        else             { in = inw; out = inwb; j = i - CVT1_E0; }
        const float4 v0 = ((const float4*)in)[j * 2];
        const float4 v1 = ((const float4*)in)[j * 2 + 1];
        int4 p;
        p.x = (int)(f2bf(v0.x) | (f2bf(v0.y) << 16));
        p.y = (int)(f2bf(v0.z) | (f2bf(v0.w) << 16));
        p.z = (int)(f2bf(v1.x) | (f2bf(v1.y) << 16));
        p.w = (int)(f2bf(v1.z) | (f2bf(v1.w) << 16));
        ((int4*)out)[j] = p;
    }
}

// ---------------------------------------------------------------------------
// Fused 3-segment cvt for step 4 (ow, xw, dtw). Targets first written here:
// owb over dead xraw, xwb/dtwb over dead inwb. Read at steps 5/6/8.
// ---------------------------------------------------------------------------
#define CVT_N_OW   1048576
#define CVT_N_XW   81920
#define CVT_N_DTW  65536
#define CVT4_E0    (CVT_N_OW)
#define CVT4_E1    (CVT4_E0 + CVT_N_XW)
#define CVT4_E2    (CVT4_E1 + CVT_N_DTW)

__global__ __launch_bounds__(256)
void cvt_step4(const float* __restrict__ ow,  ushort* __restrict__ owb,
               const float* __restrict__ xw,  ushort* __restrict__ xwb,
               const float* __restrict__ dtw, ushort* __restrict__ dtwb)
{
    for (int i = blockIdx.x * 256 + threadIdx.x; i < CVT4_E2; i += gridDim.x * 256) {
        const float* in; ushort* out; int j;
        if (i < CVT4_E0)      { in = ow;  out = owb;  j = i; }
        else if (i < CVT4_E1) { in = xw;  out = xwb;  j = i - CVT4_E0; }
        else                  { in = dtw; out = dtwb; j = i - CVT4_E1; }
        const float4 v0 = ((const float4*)in)[j * 2];
        const float4 v1 = ((const float4*)in)[j * 2 + 1];
        int4 p;
        p.x = (int)(f2bf(v0.x) | (f2bf(v0.y) << 16));
        p.y = (int)(f2bf(v0.z) | (f2bf(v0.w) << 16));
        p.z = (int)(f2bf(v1.x) | (f2bf(v1.y) << 16));
        p.w = (int)(f2bf(v1.z) | (f2bf(v1.w) << 16));
        ((int4*)out)[j] = p;
    }
}

// ---------------------------------------------------------------------------
__global__ __launch_bounds__(256)
void reduce_out4(const float* __restrict__ part, float* __restrict__ out, int n4)
{
    const int stride = M_TOK * D_MODEL / 4;   // float4 units per slice
    for (int i = blockIdx.x * 256 + threadIdx.x; i < n4; i += gridDim.x * 256) {
        const float4 a = ((const float4*)part)[i];
        const float4 b = ((const float4*)part)[i + stride];
        const float4 c = ((const float4*)part)[i + 2 * stride];
        const float4 d = ((const float4*)part)[i + 3 * stride];
        ((float4*)out)[i] = make_float4(a.x + b.x + c.x + d.x,
                                        a.y + b.y + c.y + d.y,
                                        a.z + b.z + c.z + d.z,
                                        a.w + b.w + c.w + d.w);
    }
}

// ---------------------------------------------------------------------------
// Depthwise causal conv (K=4) + bias + SiLU, m-chunked register window.
// ---------------------------------------------------------------------------
__global__ __launch_bounds__(256)
void conv_silu_k(const ushort* __restrict__ xraw,
                 const float* __restrict__ cw,
                 const float* __restrict__ cb,
                 ushort* __restrict__ xb)
{
    const int d  = (blockIdx.x << 8) + threadIdx.x;
    const int m0 = blockIdx.y << 6;
    const int l0 = m0 & (LSEQ - 1);
    const float4 w = *(const float4*)&cw[d << 2];
    const float bias = cb[d];
    float x3 = 0.f, x2 = 0.f, x1 = 0.f;
    if (l0 > 0) {
        x3 = bf2f(xraw[(size_t)(m0 - 3) * D_INNER + d]);
        x2 = bf2f(xraw[(size_t)(m0 - 2) * D_INNER + d]);
        x1 = bf2f(xraw[(size_t)(m0 - 1) * D_INNER + d]);
    }
#pragma unroll 4
    for (int i = 0; i < 64; ++i) {
        const size_t m = (size_t)m0 + i;
        const float x0 = bf2f(xraw[m * D_INNER + d]);
        float acc = bias;
        acc = fmaf(w.x, x3, acc);
        acc = fmaf(w.y, x2, acc);
        acc = fmaf(w.z, x1, acc);
        acc = fmaf(w.w, x0, acc);
        const float sg = 1.f / (1.f + expf(-acc));
        xb[m * D_INNER + d] = (ushort)f2bf(acc * sg);
        x3 = x2; x2 = x1; x1 = x0;
    }
}

// ---------------------------------------------------------------------------
__global__ __launch_bounds__(256)
void reduce_ssm(const float* __restrict__ part,
                float* __restrict__ ssmf, ushort* __restrict__ ssmb)
{
    const int i = blockIdx.x * 256 + threadIdx.x;
    float v = 0.f;
#pragma unroll
    for (int z = 0; z < 8; ++z) v += part[(size_t)z * (M_TOK * 160) + i];
    ssmf[i] = v;
    ssmb[i] = (ushort)f2bf(v);
}

// ===========================================================================
// FUSED chunked selective scan — r21: REVERT to the best-measured r18 shape
// (256 thr = 16d x 16c, LDS [16dl][17c][16s], grid (256,2); r18 total 293.3,
// scan 77.2 vs r19 80.7 / r20 103.7 — both restructures regressed), plus one
// VALU cut: fold log2e into A once per thread (a2 = a*LOG2E) and call
// v_exp_f32 directly via exp2 — removes the per-exp v_mul that __expf emits
// (32 muls per (m,d) element = 268M total). Same algebra; rounding differs
// <=1 ulp in the exp argument (4x absmax margin, |dA|<1 contraction).
// ===========================================================================
__global__ __launch_bounds__(256)
void scan_fused(const ushort* __restrict__ dtp,   // dt bf16 [M][4096]
                ushort* __restrict__ xb,          // x bf16 in / y bf16 out
                const ushort* __restrict__ gb,    // gate bf16
                const float* __restrict__ ssm,    // [M][160], B@128+s, C@144+s
                const float* __restrict__ Ap,     // [4096][16]
                const float* __restrict__ Dp)     // [4096]
{
    __shared__ float Pl[16 * 17 * 16];
    __shared__ float Ql[16 * 17 * 16];
    const int t  = threadIdx.x;
    const int dl = t & 15, c = t >> 4;
    const int d  = (blockIdx.x << 4) + dl;
    const int b  = blockIdx.y;
    const int base = (dl * 17 + c) * 16;

    float a2[16];
    *(float4*)&a2[0]  = *(const float4*)&Ap[d * 16];
    *(float4*)&a2[4]  = *(const float4*)&Ap[d * 16 + 4];
    *(float4*)&a2[8]  = *(const float4*)&Ap[d * 16 + 8];
    *(float4*)&a2[12] = *(const float4*)&Ap[d * 16 + 12];
#pragma unroll
    for (int s = 0; s < 16; ++s) a2[s] *= LOG2E;   // exp(a*x) = exp2(a2*x)
    const size_t m0 = (size_t)b * LSEQ + (size_t)c * LCHUNK;

    // ---- pass 1: per-chunk (P, q) ----
    float q[16];
#pragma unroll
    for (int s = 0; s < 16; ++s) q[s] = 0.f;
    float dtsum = 0.f;
#pragma unroll 2
    for (int l = 0; l < LCHUNK; ++l) {
        const size_t m = m0 + l;
        const float dt = bf2f(dtp[m * D_INNER + d]);
        const float xv = bf2f(xb[m * D_INNER + d]);
        const float4 B0 = *(const float4*)&ssm[m * 160 + 128];
        const float4 B1 = *(const float4*)&ssm[m * 160 + 132];
        const float4 B2 = *(const float4*)&ssm[m * 160 + 136];
        const float4 B3 = *(const float4*)&ssm[m * 160 + 140];
        const float Bv[16] = {B0.x,B0.y,B0.z,B0.w, B1.x,B1.y,B1.z,B1.w,
                              B2.x,B2.y,B2.z,B2.w, B3.x,B3.y,B3.z,B3.w};
        const float t1 = dt * xv;
#pragma unroll
        for (int s = 0; s < 16; ++s) {
            const float dA = exp2fast(dt * a2[s]);
            q[s] = fmaf(q[s], dA, t1 * Bv[s]);
        }
        dtsum += dt;
    }
#pragma unroll
    for (int s4 = 0; s4 < 4; ++s4) {
        float4 Pv;
        Pv.x = exp2fast(a2[s4 * 4 + 0] * dtsum);
        Pv.y = exp2fast(a2[s4 * 4 + 1] * dtsum);
        Pv.z = exp2fast(a2[s4 * 4 + 2] * dtsum);
        Pv.w = exp2fast(a2[s4 * 4 + 3] * dtsum);
        *(float4*)&Pl[base + s4 * 4] = Pv;
        *(float4*)&Ql[base + s4 * 4] = make_float4(q[s4*4], q[s4*4+1],
                                                   q[s4*4+2], q[s4*4+3]);
    }
    __syncthreads();

    // ---- pass 2: cross-chunk prefix; thread = (dl2, s2), 256 pairs ----
    {
        const int dl2 = t >> 4, s2 = t & 15;
        float st2 = 0.f;
#pragma unroll
        for (int c2 = 0; c2 < NCHUNK; ++c2) {
            const int idx = (dl2 * 17 + c2) * 16 + s2;
            const float Pv = Pl[idx];
            const float qv = Ql[idx];
            Ql[idx] = st2;                 // state entering chunk c2
            st2 = fmaf(st2, Pv, qv);
        }
    }
    __syncthreads();

    // ---- pass 3: rescan with correct initial state; writes y over xb ----
    float st[16];
#pragma unroll
    for (int s4 = 0; s4 < 4; ++s4)
        *(float4*)&st[s4 * 4] = *(const float4*)&Ql[base + s4 * 4];
    const float Dd = Dp[d];
#pragma unroll 2
    for (int l = 0; l < LCHUNK; ++l) {
        const size_t m = m0 + l;
        const float dt = bf2f(dtp[m * D_INNER + d]);
        const float xv = bf2f(xb[m * D_INNER + d]);
        const float gv = bf2f(gb[m * D_INNER + d]);
        const float4 B0 = *(const float4*)&ssm[m * 160 + 128];
        const float4 B1 = *(const float4*)&ssm[m * 160 + 132];
        const float4 B2 = *(const float4*)&ssm[m * 160 + 136];
        const float4 B3 = *(const float4*)&ssm[m * 160 + 140];
        const float4 C0 = *(const float4*)&ssm[m * 160 + 144];
        const float4 C1 = *(const float4*)&ssm[m * 160 + 148];
        const float4 C2 = *(const float4*)&ssm[m * 160 + 152];
        const float4 C3 = *(const float4*)&ssm[m * 160 + 156];
        const float Bv[16] = {B0.x,B0.y,B0.z,B0.w, B1.x,B1.y,B1.z,B1.w,
                              B2.x,B2.y,B2.z,B2.w, B3.x,B3.y,B3.z,B3.w};
        const float Cv[16] = {C0.x,C0.y,C0.z,C0.w, C1.x,C1.y,C1.z,C1.w,
                              C2.x,C2.y,C2.z,C2.w, C3.x,C3.y,C3.z,C3.w};
        const float t1 = dt * xv;
        float y = 0.f;
#pragma unroll
        for (int s = 0; s < 16; ++s) {
            const float dA = exp2fast(dt * a2[s]);
            st[s] = fmaf(st[s], dA, t1 * Bv[s]);
            y = fmaf(st[s], Cv[s], y);
        }
        const float yg  = fmaf(Dd, xv, y);
        const float sig = 1.f / (1.f + expf(-gv));
        xb[m * D_INNER + d] = (ushort)f2bf(yg * (gv * sig));
    }
}

// ---------------------------------------------------------------------------
extern "C" void kernel_launch(void* const* d_in, const int* in_sizes, int n_in,
                              void* d_out, int out_size, void* d_ws, size_t ws_size,
                              hipStream_t stream)
{
    (void)in_sizes; (void)n_in; (void)out_size; (void)ws_size;
    const float* hs  = (const float*)d_in[0];  // [2048,2048]
    const float* inw = (const float*)d_in[1];  // [8192,2048]
    const float* cw  = (const float*)d_in[2];  // [4096,4]
    const float* cb  = (const float*)d_in[3];  // [4096]
    const float* xw  = (const float*)d_in[4];  // [160,4096]
    const float* dtw = (const float*)d_in[5];  // [4096,128]
    const float* dtb = (const float*)d_in[6];  // [4096]
    const float* Ap  = (const float*)d_in[7];  // [4096,16]
    const float* Dp  = (const float*)d_in[8];  // [4096]
    const float* ow  = (const float*)d_in[9];  // [2048,4096]
    float* out = (float*)d_out;                // [2048,2048]

    // ------------------------------------------------------------------
    // Workspace plan: IDENTICAL to the proven round-10..19 layout
    // (100.7 MB, bf16 sizes f32-EQUIV = ushort_count/2, timeline audited).
    // xwb/dtwb live INSIDE inwb's span — written only at step 4 (after
    // in_proj consumed inwb); cvt_step1 touches only hsb+inwb.
    // ------------------------------------------------------------------
    float*  ws    = (float*)d_ws;
    float*  P     = ws;                          // [0, 16777216)        step 8
    ushort* hsb   = (ushort*)(ws + 0);           // [0, 2097152)         steps 1-2
    ushort* inwb  = (ushort*)(ws + 2097152);     // [2097152, 10485760)  steps 1-2
    ushort* dtb16 = (ushort*)(ws + 0);           // [0, 4194304)         steps 6-7
    ushort* xwb   = (ushort*)(ws + 4194304);     // [4194304, 4521984)   steps 4-5
    ushort* dtwb  = (ushort*)(ws + 4521984);     // [4521984, 4784128)   steps 4-6
    float*  ssmf  = ws + 4784128;                // [4784128, 5111808)   steps 5-7
    ushort* ssmb  = (ushort*)(ws + 5111808);     // [5111808, 5275648)   steps 5-6
    float*  part  = ws + 5275648;                // [5275648, 7897088)   step 5
    ushort* pg    = (ushort*)(ws + 10485760);    // [10485760, 14680064) steps 2-7
    ushort* xtb   = (ushort*)(ws + 16777216);    // [16777216, 20971520) steps 3-8
    ushort* xraw  = (ushort*)(ws + 20971520);    // [20971520, 25165824) steps 2-3
    ushort* owb   = (ushort*)(ws + 20971520);    // same region,         steps 4-8

    const dim3 blk(256);
    const dim3 blk512(512);

    // 1) fused cvt of in_proj inputs only (hs, inw)
    cvt_step1<<<dim3(2048), blk, 0, stream>>>(hs, hsb, inw, inwb);

    // 2) in_proj (fused x+gate): [2048 x 8192], single-phase 256^2 engine
    gemm256_1ph<<<dim3(32, 8, 1), blk512, 0, stream>>>(
        hsb, D_MODEL, inwb, D_MODEL, xraw, D_INNER, pg, D_MODEL, 5, 0);

    // 3) conv + SiLU: xraw -> xtb
    conv_silu_k<<<dim3(16, 32), blk, 0, stream>>>(xraw, cw, cb, xtb);

    // 4) fused cvt of remaining weights (ow, xw, dtw) — targets all dead now
    cvt_step4<<<dim3(2048), blk, 0, stream>>>(ow, owb, xw, xwb, dtw, dtwb);

    // 5) x_proj split-K x8 -> part; reduce -> ssmf/ssmb
    gemm_bf16_bt<<<dim3(2, 16, 8), blk512, 0, stream>>>(
        xtb, D_INNER, xwb, D_INNER, part, 160, nullptr,
        M_TOK, 160, D_INNER, 0, (size_t)M_TOK * 160);
    reduce_ssm<<<dim3(1280), blk, 0, stream>>>(part, ssmf, ssmb);

    // 6) dt_proj + softplus(+bias) -> dtb16
    gemm_bf16_bt<<<dim3(32, 16, 1), blk512, 0, stream>>>(
        ssmb, 160, dtwb, DT_RANK, dtb16, D_INNER, dtb,
        M_TOK, D_INNER, DT_RANK, 1, 0);

    // 7) FUSED chunked selective scan (+ D-skip + gate), y bf16 over xtb
    scan_fused<<<dim3(D_INNER / 16, B_SZ), blk, 0, stream>>>(
        dtb16, xtb, pg, ssmf, Ap, Dp);

    // 8) out_proj: single-phase 256^2, split-K x4 -> P; reduce4 -> out
    gemm256_1ph<<<dim3(8, 8, 4), blk512, 0, stream>>>(
        xtb, D_INNER, owb, D_INNER, P, D_MODEL, nullptr,
        D_INNER, 0, (size_t)M_TOK * D_MODEL);
    reduce_out4<<<dim3(1024), blk, 0, stream>>>(P, out, (M_TOK * D_MODEL) / 4);
}

// Round 22
// 287.842 us; speedup vs baseline: 1.1078x; 1.0020x over previous
//
#include <hip/hip_runtime.h>
#include <hip/hip_bf16.h>
#include <math.h>

#define B_SZ    2
#define LSEQ    1024
#define D_MODEL 2048
#define D_INNER 4096
#define D_STATE 16
#define DT_RANK 128
#define M_TOK   (B_SZ * LSEQ)      // 2048 token rows
#define NCHUNK  16
#define LCHUNK  (LSEQ / NCHUNK)    // 64
#define LOG2E   1.4426950408889634f

typedef __attribute__((ext_vector_type(8))) short bf16x8;
typedef __attribute__((ext_vector_type(4))) float f32x4;

__device__ __forceinline__ float softplusf_(float x) {
    return fmaxf(x, 0.f) + log1pf(expf(-fabsf(x)));
}
__device__ __forceinline__ unsigned f2bf(float f) {
    union { float f; unsigned u; } v; v.f = f;
    const unsigned u = v.u;
    return (u + 0x7fffu + ((u >> 16) & 1u)) >> 16;   // RNE, finite inputs
}
__device__ __forceinline__ float bf2f(unsigned u) {
    union { unsigned u; float f; } v; v.u = u << 16; return v.f;
}
__device__ __forceinline__ void gload16(const void* g, void* lds) {
    __builtin_amdgcn_global_load_lds(
        (const __attribute__((address_space(1))) void*)g,
        (__attribute__((address_space(3))) void*)lds, 16, 0, 0);
}
__device__ __forceinline__ float exp2fast(float x) {
    return __builtin_amdgcn_exp2f(x);    // v_exp_f32: 2^x
}
__device__ __forceinline__ float sigmoid2(float x) {
    // 1/(1+exp(-x)) with the log2e fold done once: exp(-x) = exp2(-x*LOG2E)
    return 1.f / (1.f + exp2fast(-x * LOG2E));
}

// ===========================================================================
// SINGLE-PHASE 256x256 bf16 MFMA GEMM (r17, proven at MfmaUtil ~42%).
// One vmcnt(0)+barrier per K-tile; depth-1 prefetch suffices (phase >>
// HBM latency). Race ledger: tile t reads buf[db] only (landed per previous
// barrier), stages t+1 into buf[db^1] only (disjoint; its last readers were
// tile t-1, retired before the previous barrier). vmcnt(0)+barrier at phase
// end certifies t+1 landed collectively.
// Swizzle (both sides, verified 0 conflicts): src chunk jj = j^(row&7),
// linear LDS dest; ds_read chunk ch^(row&7).
// epi: 0 = f32 (+ z*zstride, split-K); 5 = dual bf16 (col<4096 -> Cv,
// else Cv2 at col-4096, both ld = ldc).
// ===========================================================================
__global__ __launch_bounds__(512, 2)
void gemm256_1ph(const ushort* __restrict__ A, int lda,
                 const ushort* __restrict__ B, int ldb,
                 void* __restrict__ Cv, int ldc,
                 void* __restrict__ Cv2,
                 int K, int epi, size_t zstride)
{
    __shared__ ushort Lds[2][2][2][128 * 64];   // [dbuf][A/B][half][...]
    const int t    = threadIdx.x;
    const int bm   = blockIdx.y << 8, bn = blockIdx.x << 8;
    const int wave = t >> 6, lane = t & 63;
    const int wm   = wave >> 2;          // 0..1  (64-row slice within half)
    const int wn   = wave & 3;           // 0..3  (32-col slice within half)
    const int lr   = lane & 15, lh = lane >> 4;
    const int kper  = K / gridDim.z;
    const int kbase = blockIdx.z * kper;
    const int nkt   = kper >> 6;

    // staging: issue it in {0,1}: flat = t + it*512; row = flat>>3; j = flat&7
    const ushort* gsA[2]; const ushort* gsB[2];
    int dof[2];
#pragma unroll
    for (int it = 0; it < 2; ++it) {
        const int flat = t + (it << 9);
        const int row  = flat >> 3, j = flat & 7;
        const int jj   = j ^ (row & 7);
        gsA[it] = A + (size_t)(bm + row) * lda + kbase + jj * 8;
        gsB[it] = B + (size_t)(bn + row) * ldb + kbase + jj * 8;
        dof[it] = flat << 3;             // ushort offset (16 B per chunk)
    }

#define STG_A(half, kt, db) do {                                            \
    _Pragma("unroll")                                                       \
    for (int it = 0; it < 2; ++it)                                          \
        gload16(gsA[it] + (size_t)((half) * 128) * lda + (kt) * 64,         \
                &Lds[db][0][half][dof[it]]);                                \
} while (0)
#define STG_B(half, kt, db) do {                                            \
    _Pragma("unroll")                                                       \
    for (int it = 0; it < 2; ++it)                                          \
        gload16(gsB[it] + (size_t)((half) * 128) * ldb + (kt) * 64,         \
                &Lds[db][1][half][dof[it]]);                                \
} while (0)
#define RD_A(db, half) do {                                                 \
    _Pragma("unroll")                                                       \
    for (int mi = 0; mi < 4; ++mi)                                          \
    _Pragma("unroll")                                                       \
    for (int kk = 0; kk < 2; ++kk) {                                        \
        const int row_ = wm * 64 + mi * 16 + lr;                            \
        const int ch_  = ((kk << 2) + lh) ^ (row_ & 7);                     \
        af[mi * 2 + kk] = *(const bf16x8*)((const char*)Lds[db][0][half]    \
                             + row_ * 128 + (ch_ << 4));                    \
    }                                                                       \
} while (0)
#define RD_B(db, half, dst) do {                                            \
    _Pragma("unroll")                                                       \
    for (int nj = 0; nj < 2; ++nj)                                          \
    _Pragma("unroll")                                                       \
    for (int kk = 0; kk < 2; ++kk) {                                        \
        const int row_ = wn * 32 + nj * 16 + lr;                            \
        const int ch_  = ((kk << 2) + lh) ^ (row_ & 7);                     \
        dst[nj * 2 + kk] = *(const bf16x8*)((const char*)Lds[db][1][half]   \
                             + row_ * 128 + (ch_ << 4));                    \
    }                                                                       \
} while (0)
#define MFMA_PAIR(qa, qb, bfa, bfb) do {                                    \
    _Pragma("unroll")                                                       \
    for (int kk = 0; kk < 2; ++kk) {                                        \
        _Pragma("unroll")                                                   \
        for (int mi = 0; mi < 4; ++mi)                                      \
        _Pragma("unroll")                                                   \
        for (int nj = 0; nj < 2; ++nj)                                      \
            acc[qa][mi][nj] = __builtin_amdgcn_mfma_f32_16x16x32_bf16(      \
                af[mi * 2 + kk], bfa[nj * 2 + kk], acc[qa][mi][nj], 0, 0, 0);\
        _Pragma("unroll")                                                   \
        for (int mi = 0; mi < 4; ++mi)                                      \
        _Pragma("unroll")                                                   \
        for (int nj = 0; nj < 2; ++nj)                                      \
            acc[qb][mi][nj] = __builtin_amdgcn_mfma_f32_16x16x32_bf16(      \
                af[mi * 2 + kk], bfb[nj * 2 + kk], acc[qb][mi][nj], 0, 0, 0);\
    }                                                                       \
} while (0)

    f32x4 acc[4][4][2];
#pragma unroll
    for (int q = 0; q < 4; ++q)
#pragma unroll
        for (int i = 0; i < 4; ++i)
#pragma unroll
            for (int j = 0; j < 2; ++j) {
                acc[q][i][j][0] = 0.f; acc[q][i][j][1] = 0.f;
                acc[q][i][j][2] = 0.f; acc[q][i][j][3] = 0.f;
            }

    bf16x8 af[8], bf0[4], bf1[4];

    // prologue: stage tile 0 fully, drain, barrier
    STG_A(0, 0, 0); STG_B(0, 0, 0); STG_B(1, 0, 0); STG_A(1, 0, 0);
    asm volatile("s_waitcnt vmcnt(0)" ::: "memory");
    __builtin_amdgcn_s_barrier();

    for (int kt = 0; kt < nkt; ++kt) {
        const int db = kt & 1;
        RD_A(db, 0); RD_B(db, 0, bf0); RD_B(db, 1, bf1);
        if (kt + 1 < nkt) {
            STG_A(0, kt + 1, db ^ 1); STG_B(0, kt + 1, db ^ 1);
            STG_B(1, kt + 1, db ^ 1); STG_A(1, kt + 1, db ^ 1);
        }
        MFMA_PAIR(0, 1, bf0, bf1);
        RD_A(db, 1);
        MFMA_PAIR(2, 3, bf1, bf0);
        asm volatile("s_waitcnt vmcnt(0)" ::: "memory");
        __builtin_amdgcn_s_barrier();
    }
#undef STG_A
#undef STG_B
#undef RD_A
#undef RD_B
#undef MFMA_PAIR

    float*  C  = (float*)Cv + (size_t)blockIdx.z * zstride;
    ushort* Cb = (ushort*)Cv;
    ushort* C2 = (ushort*)Cv2;
#pragma unroll
    for (int q = 0; q < 4; ++q) {
        const int mh = q >> 1;                        // 0,0,1,1
        const int nh = (q == 1 || q == 2) ? 1 : 0;    // 0,1,1,0
#pragma unroll
        for (int mi = 0; mi < 4; ++mi) {
#pragma unroll
            for (int nj = 0; nj < 2; ++nj) {
                const int col  = bn + nh * 128 + wn * 32 + nj * 16 + lr;
                const int row0 = bm + mh * 128 + wm * 64 + mi * 16 + (lh << 2);
#pragma unroll
                for (int r = 0; r < 4; ++r) {
                    const float v = acc[q][mi][nj][r];
                    if (epi == 0) {
                        C[(size_t)(row0 + r) * ldc + col] = v;
                    } else {  // epi == 5: dual bf16 (fused in_proj)
                        if (col < D_INNER)
                            Cb[(size_t)(row0 + r) * ldc + col] = (ushort)f2bf(v);
                        else
                            C2[(size_t)(row0 + r) * ldc + (col - D_INNER)] = (ushort)f2bf(v);
                    }
                }
            }
        }
    }
}

// ---------------------------------------------------------------------------
// r8 128x128 dbuf GEMM (skinny x_proj / dt_proj shapes). Leading barrier
// KEPT: it pairs with the stage-landing vmcnt (stage-before-read structure).
// epi: 0 = f32 store (split-K via z*zstride); 1 = softplus(v+bias) -> bf16.
// ---------------------------------------------------------------------------
__global__ __launch_bounds__(512, 4)
void gemm_bf16_bt(const ushort* __restrict__ A, int lda,
                  const ushort* __restrict__ B, int ldb,
                  void* __restrict__ Cv, int ldc,
                  const float* __restrict__ bias,
                  int M, int N, int K, int epi, size_t zstride)
{
    __shared__ ushort As[2][128 * 64];
    __shared__ ushort Bs[2][128 * 64];
    const int t    = threadIdx.x;
    const int bm   = blockIdx.y << 7, bn = blockIdx.x << 7;
    const int wave = t >> 6, lane = t & 63;
    const int wr   = (wave >> 2) << 6;
    const int wc   = (wave & 3) << 5;
    const int lr   = lane & 15, lh = lane >> 4;
    const int kper  = K / gridDim.z;
    const int kbase = blockIdx.z * kper;
    const int nkt   = kper >> 6;

    const ushort* ga[2]; const ushort* gb[2];
    int ldof[2];
#pragma unroll
    for (int it = 0; it < 2; ++it) {
        const int seg = wave + (it << 3);
        const int row = (seg << 3) + (lane >> 3);
        const int jj  = (lane & 7) ^ ((lane >> 3) & 7);
        ga[it] = A + (size_t)(bm + row) * lda + kbase + jj * 8;
        int gn = bn + row; gn = gn < N ? gn : N - 1;
        gb[it] = B + (size_t)gn * ldb + kbase + jj * 8;
        ldof[it] = seg << 9;
    }

#define STAGE(bsel) do {                                                \
    _Pragma("unroll")                                                   \
    for (int it = 0; it < 2; ++it) {                                    \
        gload16(ga[it], &As[bsel][ldof[it]]);                           \
        gload16(gb[it], &Bs[bsel][ldof[it]]);                           \
        ga[it] += 64; gb[it] += 64;                                     \
    }                                                                   \
} while (0)

    f32x4 acc[4][2];
#pragma unroll
    for (int i = 0; i < 4; ++i)
#pragma unroll
        for (int j = 0; j < 2; ++j) {
            acc[i][j][0] = 0.f; acc[i][j][1] = 0.f;
            acc[i][j][2] = 0.f; acc[i][j][3] = 0.f;
        }

    STAGE(0);
    for (int kt = 0; kt < nkt; ++kt) {
        const int cur = kt & 1;
        if (kt + 1 < nkt) {
            STAGE(cur ^ 1);
            asm volatile("s_waitcnt vmcnt(4)" ::: "memory");
        } else {
            asm volatile("s_waitcnt vmcnt(0)" ::: "memory");
        }
        __builtin_amdgcn_s_barrier();

        const char* Ab = (const char*)As[cur];
        const char* Bb = (const char*)Bs[cur];
#pragma unroll
        for (int kk = 0; kk < 2; ++kk) {
            bf16x8 af[4], bf[2];
#pragma unroll
            for (int mi = 0; mi < 4; ++mi) {
                const int row = wr + (mi << 4) + lr;
                const int ch  = ((kk << 2) + lh) ^ (row & 7);
                af[mi] = *(const bf16x8*)(Ab + row * 128 + (ch << 4));
            }
#pragma unroll
            for (int nj = 0; nj < 2; ++nj) {
                const int row = wc + (nj << 4) + lr;
                const int ch  = ((kk << 2) + lh) ^ (row & 7);
                bf[nj] = *(const bf16x8*)(Bb + row * 128 + (ch << 4));
            }
#pragma unroll
            for (int mi = 0; mi < 4; ++mi)
#pragma unroll
                for (int nj = 0; nj < 2; ++nj)
                    acc[mi][nj] = __builtin_amdgcn_mfma_f32_16x16x32_bf16(
                        af[mi], bf[nj], acc[mi][nj], 0, 0, 0);
        }
        __builtin_amdgcn_s_barrier();
    }
#undef STAGE

    float*  C  = (float*)Cv + (size_t)blockIdx.z * zstride;
    ushort* Cb = (ushort*)Cv;
#pragma unroll
    for (int mi = 0; mi < 4; ++mi) {
#pragma unroll
        for (int nj = 0; nj < 2; ++nj) {
            const int col  = bn + wc + (nj << 4) + lr;
            const int row0 = bm + wr + (mi << 4) + (lh << 2);
            if (col < N) {
#pragma unroll
                for (int r = 0; r < 4; ++r) {
                    const float v = acc[mi][nj][r];
                    if (epi == 0)
                        C[(size_t)(row0 + r) * ldc + col] = v;
                    else
                        Cb[(size_t)(row0 + r) * ldc + col] =
                            (ushort)f2bf(softplusf_(v + bias[col]));
                }
            }
        }
    }
}

// ---------------------------------------------------------------------------
// Fused 2-segment cvt for step 1 (hs, inw). Targets disjoint from all live
// data.
// ---------------------------------------------------------------------------
#define CVT_N_HS   524288
#define CVT_N_INW  2097152
#define CVT1_E0    (CVT_N_HS)
#define CVT1_E1    (CVT1_E0 + CVT_N_INW)

__global__ __launch_bounds__(256)
void cvt_step1(const float* __restrict__ hs,  ushort* __restrict__ hsb,
               const float* __restrict__ inw, ushort* __restrict__ inwb)
{
    for (int i = blockIdx.x * 256 + threadIdx.x; i < CVT1_E1; i += gridDim.x * 256) {
        const float* in; ushort* out; int j;
        if (i < CVT1_E0) { in = hs;  out = hsb;  j = i; }
        else             { in = inw; out = inwb; j = i - CVT1_E0; }
        const float4 v0 = ((const float4*)in)[j * 2];
        const float4 v1 = ((const float4*)in)[j * 2 + 1];
        int4 p;
        p.x = (int)(f2bf(v0.x) | (f2bf(v0.y) << 16));
        p.y = (int)(f2bf(v0.z) | (f2bf(v0.w) << 16));
        p.z = (int)(f2bf(v1.x) | (f2bf(v1.y) << 16));
        p.w = (int)(f2bf(v1.z) | (f2bf(v1.w) << 16));
        ((int4*)out)[j] = p;
    }
}

// ---------------------------------------------------------------------------
// Fused 3-segment cvt for step 4 (ow, xw, dtw). Targets first written here:
// owb over dead xraw, xwb/dtwb over dead inwb. Read at steps 5/6/8.
// ---------------------------------------------------------------------------
#define CVT_N_OW   1048576
#define CVT_N_XW   81920
#define CVT_N_DTW  65536
#define CVT4_E0    (CVT_N_OW)
#define CVT4_E1    (CVT4_E0 + CVT_N_XW)
#define CVT4_E2    (CVT4_E1 + CVT_N_DTW)

__global__ __launch_bounds__(256)
void cvt_step4(const float* __restrict__ ow,  ushort* __restrict__ owb,
               const float* __restrict__ xw,  ushort* __restrict__ xwb,
               const float* __restrict__ dtw, ushort* __restrict__ dtwb)
{
    for (int i = blockIdx.x * 256 + threadIdx.x; i < CVT4_E2; i += gridDim.x * 256) {
        const float* in; ushort* out; int j;
        if (i < CVT4_E0)      { in = ow;  out = owb;  j = i; }
        else if (i < CVT4_E1) { in = xw;  out = xwb;  j = i - CVT4_E0; }
        else                  { in = dtw; out = dtwb; j = i - CVT4_E1; }
        const float4 v0 = ((const float4*)in)[j * 2];
        const float4 v1 = ((const float4*)in)[j * 2 + 1];
        int4 p;
        p.x = (int)(f2bf(v0.x) | (f2bf(v0.y) << 16));
        p.y = (int)(f2bf(v0.z) | (f2bf(v0.w) << 16));
        p.z = (int)(f2bf(v1.x) | (f2bf(v1.y) << 16));
        p.w = (int)(f2bf(v1.z) | (f2bf(v1.w) << 16));
        ((int4*)out)[j] = p;
    }
}

// ---------------------------------------------------------------------------
__global__ __launch_bounds__(256)
void reduce_out4(const float* __restrict__ part, float* __restrict__ out, int n4)
{
    const int stride = M_TOK * D_MODEL / 4;   // float4 units per slice
    for (int i = blockIdx.x * 256 + threadIdx.x; i < n4; i += gridDim.x * 256) {
        const float4 a = ((const float4*)part)[i];
        const float4 b = ((const float4*)part)[i + stride];
        const float4 c = ((const float4*)part)[i + 2 * stride];
        const float4 d = ((const float4*)part)[i + 3 * stride];
        ((float4*)out)[i] = make_float4(a.x + b.x + c.x + d.x,
                                        a.y + b.y + c.y + d.y,
                                        a.z + b.z + c.z + d.z,
                                        a.w + b.w + c.w + d.w);
    }
}

// ---------------------------------------------------------------------------
// Depthwise causal conv (K=4) + bias + SiLU, m-chunked register window.
// r22: sigmoid via exp2 (folds __expf's implicit log2e mul).
// ---------------------------------------------------------------------------
__global__ __launch_bounds__(256)
void conv_silu_k(const ushort* __restrict__ xraw,
                 const float* __restrict__ cw,
                 const float* __restrict__ cb,
                 ushort* __restrict__ xb)
{
    const int d  = (blockIdx.x << 8) + threadIdx.x;
    const int m0 = blockIdx.y << 6;
    const int l0 = m0 & (LSEQ - 1);
    const float4 w = *(const float4*)&cw[d << 2];
    const float bias = cb[d];
    float x3 = 0.f, x2 = 0.f, x1 = 0.f;
    if (l0 > 0) {
        x3 = bf2f(xraw[(size_t)(m0 - 3) * D_INNER + d]);
        x2 = bf2f(xraw[(size_t)(m0 - 2) * D_INNER + d]);
        x1 = bf2f(xraw[(size_t)(m0 - 1) * D_INNER + d]);
    }
#pragma unroll 4
    for (int i = 0; i < 64; ++i) {
        const size_t m = (size_t)m0 + i;
        const float x0 = bf2f(xraw[m * D_INNER + d]);
        float acc = bias;
        acc = fmaf(w.x, x3, acc);
        acc = fmaf(w.y, x2, acc);
        acc = fmaf(w.z, x1, acc);
        acc = fmaf(w.w, x0, acc);
        xb[m * D_INNER + d] = (ushort)f2bf(acc * sigmoid2(acc));
        x3 = x2; x2 = x1; x1 = x0;
    }
}

// ---------------------------------------------------------------------------
__global__ __launch_bounds__(256)
void reduce_ssm(const float* __restrict__ part,
                float* __restrict__ ssmf, ushort* __restrict__ ssmb)
{
    const int i = blockIdx.x * 256 + threadIdx.x;
    float v = 0.f;
#pragma unroll
    for (int z = 0; z < 8; ++z) v += part[(size_t)z * (M_TOK * 160) + i];
    ssmf[i] = v;
    ssmb[i] = (ushort)f2bf(v);
}

// ===========================================================================
// FUSED chunked selective scan (r21 proven shape: 256 thr = 16d x 16c,
// LDS [16dl][17c][16s], grid (256,2); exp2-folded A). r22: gate sigmoid
// also via exp2.
// ===========================================================================
__global__ __launch_bounds__(256)
void scan_fused(const ushort* __restrict__ dtp,   // dt bf16 [M][4096]
                ushort* __restrict__ xb,          // x bf16 in / y bf16 out
                const ushort* __restrict__ gb,    // gate bf16
                const float* __restrict__ ssm,    // [M][160], B@128+s, C@144+s
                const float* __restrict__ Ap,     // [4096][16]
                const float* __restrict__ Dp)     // [4096]
{
    __shared__ float Pl[16 * 17 * 16];
    __shared__ float Ql[16 * 17 * 16];
    const int t  = threadIdx.x;
    const int dl = t & 15, c = t >> 4;
    const int d  = (blockIdx.x << 4) + dl;
    const int b  = blockIdx.y;
    const int base = (dl * 17 + c) * 16;

    float a2[16];
    *(float4*)&a2[0]  = *(const float4*)&Ap[d * 16];
    *(float4*)&a2[4]  = *(const float4*)&Ap[d * 16 + 4];
    *(float4*)&a2[8]  = *(const float4*)&Ap[d * 16 + 8];
    *(float4*)&a2[12] = *(const float4*)&Ap[d * 16 + 12];
#pragma unroll
    for (int s = 0; s < 16; ++s) a2[s] *= LOG2E;   // exp(a*x) = exp2(a2*x)
    const size_t m0 = (size_t)b * LSEQ + (size_t)c * LCHUNK;

    // ---- pass 1: per-chunk (P, q) ----
    float q[16];
#pragma unroll
    for (int s = 0; s < 16; ++s) q[s] = 0.f;
    float dtsum = 0.f;
#pragma unroll 2
    for (int l = 0; l < LCHUNK; ++l) {
        const size_t m = m0 + l;
        const float dt = bf2f(dtp[m * D_INNER + d]);
        const float xv = bf2f(xb[m * D_INNER + d]);
        const float4 B0 = *(const float4*)&ssm[m * 160 + 128];
        const float4 B1 = *(const float4*)&ssm[m * 160 + 132];
        const float4 B2 = *(const float4*)&ssm[m * 160 + 136];
        const float4 B3 = *(const float4*)&ssm[m * 160 + 140];
        const float Bv[16] = {B0.x,B0.y,B0.z,B0.w, B1.x,B1.y,B1.z,B1.w,
                              B2.x,B2.y,B2.z,B2.w, B3.x,B3.y,B3.z,B3.w};
        const float t1 = dt * xv;
#pragma unroll
        for (int s = 0; s < 16; ++s) {
            const float dA = exp2fast(dt * a2[s]);
            q[s] = fmaf(q[s], dA, t1 * Bv[s]);
        }
        dtsum += dt;
    }
#pragma unroll
    for (int s4 = 0; s4 < 4; ++s4) {
        float4 Pv;
        Pv.x = exp2fast(a2[s4 * 4 + 0] * dtsum);
        Pv.y = exp2fast(a2[s4 * 4 + 1] * dtsum);
        Pv.z = exp2fast(a2[s4 * 4 + 2] * dtsum);
        Pv.w = exp2fast(a2[s4 * 4 + 3] * dtsum);
        *(float4*)&Pl[base + s4 * 4] = Pv;
        *(float4*)&Ql[base + s4 * 4] = make_float4(q[s4*4], q[s4*4+1],
                                                   q[s4*4+2], q[s4*4+3]);
    }
    __syncthreads();

    // ---- pass 2: cross-chunk prefix; thread = (dl2, s2), 256 pairs ----
    {
        const int dl2 = t >> 4, s2 = t & 15;
        float st2 = 0.f;
#pragma unroll
        for (int c2 = 0; c2 < NCHUNK; ++c2) {
            const int idx = (dl2 * 17 + c2) * 16 + s2;
            const float Pv = Pl[idx];
            const float qv = Ql[idx];
            Ql[idx] = st2;                 // state entering chunk c2
            st2 = fmaf(st2, Pv, qv);
        }
    }
    __syncthreads();

    // ---- pass 3: rescan with correct initial state; writes y over xb ----
    float st[16];
#pragma unroll
    for (int s4 = 0; s4 < 4; ++s4)
        *(float4*)&st[s4 * 4] = *(const float4*)&Ql[base + s4 * 4];
    const float Dd = Dp[d];
#pragma unroll 2
    for (int l = 0; l < LCHUNK; ++l) {
        const size_t m = m0 + l;
        const float dt = bf2f(dtp[m * D_INNER + d]);
        const float xv = bf2f(xb[m * D_INNER + d]);
        const float gv = bf2f(gb[m * D_INNER + d]);
        const float4 B0 = *(const float4*)&ssm[m * 160 + 128];
        const float4 B1 = *(const float4*)&ssm[m * 160 + 132];
        const float4 B2 = *(const float4*)&ssm[m * 160 + 136];
        const float4 B3 = *(const float4*)&ssm[m * 160 + 140];
        const float4 C0 = *(const float4*)&ssm[m * 160 + 144];
        const float4 C1 = *(const float4*)&ssm[m * 160 + 148];
        const float4 C2 = *(const float4*)&ssm[m * 160 + 152];
        const float4 C3 = *(const float4*)&ssm[m * 160 + 156];
        const float Bv[16] = {B0.x,B0.y,B0.z,B0.w, B1.x,B1.y,B1.z,B1.w,
                              B2.x,B2.y,B2.z,B2.w, B3.x,B3.y,B3.z,B3.w};
        const float Cv[16] = {C0.x,C0.y,C0.z,C0.w, C1.x,C1.y,C1.z,C1.w,
                              C2.x,C2.y,C2.z,C2.w, C3.x,C3.y,C3.z,C3.w};
        const float t1 = dt * xv;
        float y = 0.f;
#pragma unroll
        for (int s = 0; s < 16; ++s) {
            const float dA = exp2fast(dt * a2[s]);
            st[s] = fmaf(st[s], dA, t1 * Bv[s]);
            y = fmaf(st[s], Cv[s], y);
        }
        const float yg = fmaf(Dd, xv, y);
        xb[m * D_INNER + d] = (ushort)f2bf(yg * (gv * sigmoid2(gv)));
    }
}

// ---------------------------------------------------------------------------
extern "C" void kernel_launch(void* const* d_in, const int* in_sizes, int n_in,
                              void* d_out, int out_size, void* d_ws, size_t ws_size,
                              hipStream_t stream)
{
    (void)in_sizes; (void)n_in; (void)out_size; (void)ws_size;
    const float* hs  = (const float*)d_in[0];  // [2048,2048]
    const float* inw = (const float*)d_in[1];  // [8192,2048]
    const float* cw  = (const float*)d_in[2];  // [4096,4]
    const float* cb  = (const float*)d_in[3];  // [4096]
    const float* xw  = (const float*)d_in[4];  // [160,4096]
    const float* dtw = (const float*)d_in[5];  // [4096,128]
    const float* dtb = (const float*)d_in[6];  // [4096]
    const float* Ap  = (const float*)d_in[7];  // [4096,16]
    const float* Dp  = (const float*)d_in[8];  // [4096]
    const float* ow  = (const float*)d_in[9];  // [2048,4096]
    float* out = (float*)d_out;                // [2048,2048]

    // ------------------------------------------------------------------
    // Workspace plan: IDENTICAL to the proven round-10..21 layout
    // (100.7 MB, bf16 sizes f32-EQUIV = ushort_count/2, timeline audited).
    // xwb/dtwb live INSIDE inwb's span — written only at step 4 (after
    // in_proj consumed inwb); cvt_step1 touches only hsb+inwb.
    // ------------------------------------------------------------------
    float*  ws    = (float*)d_ws;
    float*  P     = ws;                          // [0, 16777216)        step 8
    ushort* hsb   = (ushort*)(ws + 0);           // [0, 2097152)         steps 1-2
    ushort* inwb  = (ushort*)(ws + 2097152);     // [2097152, 10485760)  steps 1-2
    ushort* dtb16 = (ushort*)(ws + 0);           // [0, 4194304)         steps 6-7
    ushort* xwb   = (ushort*)(ws + 4194304);     // [4194304, 4521984)   steps 4-5
    ushort* dtwb  = (ushort*)(ws + 4521984);     // [4521984, 4784128)   steps 4-6
    float*  ssmf  = ws + 4784128;                // [4784128, 5111808)   steps 5-7
    ushort* ssmb  = (ushort*)(ws + 5111808);     // [5111808, 5275648)   steps 5-6
    float*  part  = ws + 5275648;                // [5275648, 7897088)   step 5
    ushort* pg    = (ushort*)(ws + 10485760);    // [10485760, 14680064) steps 2-7
    ushort* xtb   = (ushort*)(ws + 16777216);    // [16777216, 20971520) steps 3-8
    ushort* xraw  = (ushort*)(ws + 20971520);    // [20971520, 25165824) steps 2-3
    ushort* owb   = (ushort*)(ws + 20971520);    // same region,         steps 4-8

    const dim3 blk(256);
    const dim3 blk512(512);

    // 1) fused cvt of in_proj inputs only (hs, inw)
    cvt_step1<<<dim3(2048), blk, 0, stream>>>(hs, hsb, inw, inwb);

    // 2) in_proj (fused x+gate): [2048 x 8192], single-phase 256^2 engine
    gemm256_1ph<<<dim3(32, 8, 1), blk512, 0, stream>>>(
        hsb, D_MODEL, inwb, D_MODEL, xraw, D_INNER, pg, D_MODEL, 5, 0);

    // 3) conv + SiLU: xraw -> xtb
    conv_silu_k<<<dim3(16, 32), blk, 0, stream>>>(xraw, cw, cb, xtb);

    // 4) fused cvt of remaining weights (ow, xw, dtw) — targets all dead now
    cvt_step4<<<dim3(2048), blk, 0, stream>>>(ow, owb, xw, xwb, dtw, dtwb);

    // 5) x_proj split-K x8 -> part; reduce -> ssmf/ssmb
    gemm_bf16_bt<<<dim3(2, 16, 8), blk512, 0, stream>>>(
        xtb, D_INNER, xwb, D_INNER, part, 160, nullptr,
        M_TOK, 160, D_INNER, 0, (size_t)M_TOK * 160);
    reduce_ssm<<<dim3(1280), blk, 0, stream>>>(part, ssmf, ssmb);

    // 6) dt_proj + softplus(+bias) -> dtb16
    gemm_bf16_bt<<<dim3(32, 16, 1), blk512, 0, stream>>>(
        ssmb, 160, dtwb, DT_RANK, dtb16, D_INNER, dtb,
        M_TOK, D_INNER, DT_RANK, 1, 0);

    // 7) FUSED chunked selective scan (+ D-skip + gate), y bf16 over xtb
    scan_fused<<<dim3(D_INNER / 16, B_SZ), blk, 0, stream>>>(
        dtb16, xtb, pg, ssmf, Ap, Dp);

    // 8) out_proj: single-phase 256^2, split-K x4 -> P; reduce4 -> out
    gemm256_1ph<<<dim3(8, 8, 4), blk512, 0, stream>>>(
        xtb, D_INNER, owb, D_INNER, P, D_MODEL, nullptr,
        D_INNER, 0, (size_t)M_TOK * D_MODEL);
    reduce_out4<<<dim3(1024), blk, 0, stream>>>(P, out, (M_TOK * D_MODEL) / 4);
}